// Round 5
// baseline (420.228 us; speedup 1.0000x reference)
//
#include <hip/hip_runtime.h>
#include <hip/hip_bf16.h>
#include <cstdint>
#include <cstddef>

#define EPS 1e-8f

typedef __attribute__((ext_vector_type(8))) short short8;
typedef __attribute__((ext_vector_type(4))) float floatx4;

static constexpr int Bb = 16, Nn = 1024, Dd = 256, Kk = 256;
static constexpr int M = Bb * Nn;                      // 16384 rows per modality
static constexpr size_t PM = (size_t)M * 256;          // 4,194,304 elements per modality plane

// d_out element offsets (f32)
static constexpr size_t OUT_Z      = 0;
static constexpr size_t OUT_ASSIGN = 2 * PM;
static constexpr size_t OUT_SIM    = 4 * PM;
static constexpr size_t OUT_SEM    = 6 * PM;

// ws byte offsets
static constexpr size_t OFF_XN  = 0;                   // xn bf16 2*PM (aliased by abf later)
static constexpr size_t OFF_QB  = 16777216;            // q0 bf16 2*PM
static constexpr size_t OFF_PN  = 33554432;            // pn bf16 2*64K
static constexpr size_t OFF_PNT = 33816576;            // pnt bf16
static constexpr size_t OFF_U   = 34078720;            // (unused now, kept for layout)
static constexpr size_t OFF_T   = 34209792;            // Tg 32 f32
static constexpr size_t OFF_SC  = 34209920;            // Sc 5*32*256 f32 (in 196608 slot)
static constexpr size_t OFF_CS  = 34406528;            // cs 2*16*256 f32
static constexpr size_t OFF_CTR = 34439296;            // barrier counters 5*32 int (pad 1024)
static constexpr size_t ZERO_OFF = OFF_T;
static constexpr size_t ZERO_SZ  = 128 + 196608 + 32768 + 1024;
static constexpr int    NZ_FLOATS = (int)(ZERO_SZ / 4);

__device__ __forceinline__ unsigned short f2bf(float f) {
    unsigned int b = __float_as_uint(f);
    b += 0x7fffu + ((b >> 16) & 1u);          // RNE
    return (unsigned short)(b >> 16);
}
__device__ __forceinline__ float bf2f(unsigned short u) {
    return __uint_as_float(((unsigned int)u) << 16);
}

typedef const __attribute__((address_space(1))) unsigned int* gas_u32p;
typedef __attribute__((address_space(3))) unsigned int* las_u32p;
__device__ __forceinline__ void lds_cp16(const unsigned short* g, short* l) {
    __builtin_amdgcn_global_load_lds((gas_u32p)g, (las_u32p)l, 16, 0, 0);
}

// ---------------- x row-normalize -> bf16 ----------------
__global__ __launch_bounds__(256) void prep_kernel(const float* __restrict__ fr,
                                                   const float* __restrict__ fs,
                                                   unsigned short* __restrict__ xn) {
    int mod = blockIdx.y;
    int row = blockIdx.x * 4 + (threadIdx.x >> 6);
    int lane = threadIdx.x & 63;
    const float* src = (mod ? fs : fr) + (size_t)row * 256;
    float4 v = ((const float4*)src)[lane];
    float ss = v.x * v.x + v.y * v.y + v.z * v.z + v.w * v.w;
    #pragma unroll
    for (int m = 1; m < 64; m <<= 1) ss += __shfl_xor(ss, m);
    float sc = 1.0f / (sqrtf(ss) + EPS);
    ushort4 u4;
    u4.x = f2bf(v.x * sc); u4.y = f2bf(v.y * sc);
    u4.z = f2bf(v.z * sc); u4.w = f2bf(v.w * sc);
    *(ushort4*)(xn + (size_t)mod * PM + (size_t)row * 256 + lane * 4) = u4;
}

// ---------------- proto normalize (+ fused scratch zeroing) ----------------
__global__ __launch_bounds__(64) void proto_kernel(const float* __restrict__ pr,
                                                   const float* __restrict__ ps,
                                                   unsigned short* __restrict__ pn,
                                                   unsigned short* __restrict__ pnt,
                                                   float* __restrict__ zp) {
    int gid = blockIdx.x * 64 + threadIdx.x;           // 0..32767
    for (int i = gid; i < NZ_FLOATS; i += 32768) zp[i] = 0.f;

    int row = blockIdx.x & 255;
    int mod = blockIdx.x >> 8;
    const float* p = (mod ? ps : pr) + (size_t)row * 256;
    int lane = threadIdx.x;
    float4 v = ((const float4*)p)[lane];
    float ss = v.x * v.x + v.y * v.y + v.z * v.z + v.w * v.w;
    #pragma unroll
    for (int m = 1; m < 64; m <<= 1) ss += __shfl_xor(ss, m);
    float sc = 1.0f / (sqrtf(ss) + EPS);
    ushort4 u4;
    u4.x = f2bf(v.x * sc); u4.y = f2bf(v.y * sc);
    u4.z = f2bf(v.z * sc); u4.w = f2bf(v.w * sc);
    *(ushort4*)(pn + (size_t)mod * 65536 + (size_t)row * 256 + lane * 4) = u4;
    unsigned short* pt = pnt + (size_t)mod * 65536 + row;
    pt[(size_t)(lane * 4 + 0) * 256] = u4.x;
    pt[(size_t)(lane * 4 + 1) * 256] = u4.y;
    pt[(size_t)(lane * 4 + 2) * 256] = u4.z;
    pt[(size_t)(lane * 4 + 3) * 256] = u4.w;
}

// ---------------- MFMA GEMM, 128x128 tile, BK=64, global_load_lds + XOR swizzle ----------
template <int MODE>
__global__ __launch_bounds__(256) void gemm_kernel(const unsigned short* __restrict__ Asrc,
                                                   const unsigned short* __restrict__ Bsrc,
                                                   unsigned short* __restrict__ qb,
                                                   float* __restrict__ doutf,
                                                   float* __restrict__ Tg) {
    __shared__ short Al[8192];   // 128 rows x 64 shorts (8 chunks of 16B), chunk-swizzled
    __shared__ short Bl[8192];

    int bx = blockIdx.x;          // col tile 0..1
    int by = blockIdx.y;          // row tile 0..127
    int mod = blockIdx.z;
    int t = threadIdx.x;
    int lane = t & 63, wv = t >> 6;
    int wrow = (wv >> 1) * 64, wcol = (wv & 1) * 64;
    int g = lane >> 4, ml = lane & 15;

    const unsigned short* A0 = Asrc + (size_t)mod * PM + (size_t)by * 128 * 256;
    const unsigned short* B0 = Bsrc + (size_t)mod * 65536 + (size_t)bx * 128 * 256;

    floatx4 acc[4][4];
    #pragma unroll
    for (int i = 0; i < 4; i++)
        #pragma unroll
        for (int j = 0; j < 4; j++) acc[i][j] = (floatx4){0.f, 0.f, 0.f, 0.f};

    for (int kh = 0; kh < 4; kh++) {
        #pragma unroll
        for (int i = 0; i < 4; i++) {
            int sI = i * 256 + t;                 // linear 16B-slot index
            int r = sI >> 3, cs = sI & 7;
            int cg = cs ^ (r & 7);
            size_t goff = (size_t)r * 256 + kh * 64 + cg * 8;
            lds_cp16(A0 + goff, &Al[sI * 8]);
            lds_cp16(B0 + goff, &Bl[sI * 8]);
        }
        __syncthreads();
        #pragma unroll
        for (int ks = 0; ks < 2; ks++) {
            short8 af[4], bfr[4];
            int c = ks * 4 + g;
            #pragma unroll
            for (int mt = 0; mt < 4; mt++) {
                int row = wrow + mt * 16 + ml;
                af[mt] = *(const short8*)&Al[row * 64 + (c ^ (row & 7)) * 8];
            }
            #pragma unroll
            for (int nt = 0; nt < 4; nt++) {
                int row = wcol + nt * 16 + ml;
                bfr[nt] = *(const short8*)&Bl[row * 64 + (c ^ (row & 7)) * 8];
            }
            #pragma unroll
            for (int mt = 0; mt < 4; mt++)
                #pragma unroll
                for (int nt = 0; nt < 4; nt++)
                    acc[mt][nt] = __builtin_amdgcn_mfma_f32_16x16x32_bf16(af[mt], bfr[nt], acc[mt][nt], 0, 0, 0);
        }
        __syncthreads();
    }

    int g4 = g << 2;
    float tsum = 0.f;
    #pragma unroll
    for (int mt = 0; mt < 4; mt++)
        #pragma unroll
        for (int nt = 0; nt < 4; nt++)
            #pragma unroll
            for (int reg = 0; reg < 4; reg++) {
                float s = acc[mt][nt][reg];
                int row = by * 128 + wrow + mt * 16 + g4 + reg;
                int col = bx * 128 + wcol + nt * 16 + ml;
                size_t idx = (size_t)row * 256 + col;
                if (MODE == 0) {
                    doutf[OUT_SIM + (size_t)mod * PM + idx] = s;
                    unsigned short eb = f2bf(__expf(s * 20.0f));   // exp(sim/tau), tau=0.05
                    qb[(size_t)mod * PM + idx] = eb;
                    tsum += bf2f(eb);
                } else {
                    doutf[OUT_Z + (size_t)mod * PM + idx] = s;
                }
            }
    if (MODE == 0) {
        #pragma unroll
        for (int mk = 1; mk < 64; mk <<= 1) tsum += __shfl_xor(tsum, mk);
        if (lane == 0) atomicAdd(&Tg[mod * 16 + (by >> 3)], tsum);
    }
}

// ---------------- Persistent fused Sinkhorn: all 5 iterations + final in ONE kernel ------
// 512 blocks (16 tiles x 16 batches x 2 mods), 64 rows/block held in LDS for the whole
// chain. u is block-local. Column sums cross 16 blocks per (b,mod) group via global
// atomics + spin barrier (all blocks co-resident: 256 thr, ~40KB LDS -> >=2 blocks/CU
// capacity = 512 slots >= grid).
__global__ __launch_bounds__(256) void sinkhorn_kernel(const unsigned short* __restrict__ qbg,
                                                       const float* __restrict__ Tg,
                                                       float* __restrict__ Sc,
                                                       int* __restrict__ ctr,
                                                       float* __restrict__ cs,
                                                       float* __restrict__ doutf,
                                                       unsigned short* __restrict__ abf) {
    __shared__ unsigned short q0t[64 * 264];   // 64 rows x 256 cols, +8 shorts pad
    __shared__ float vcur[256];
    __shared__ float unl[64];
    __shared__ float wacc[4][256];

    int tile = blockIdx.x, b = blockIdx.y, mod = blockIdx.z;
    int grp = mod * 16 + b;
    int t = threadIdx.x;
    int wv = t >> 6, lane = t & 63;

    size_t rowbase = (size_t)b * 1024 + (size_t)tile * 64;           // within modality
    const unsigned short* gsrc = qbg + ((size_t)mod * M + rowbase) * 256;

    // ---- load q0 tile into LDS (coalesced 16B slots) ----
    #pragma unroll
    for (int it = 0; it < 8; it++) {
        int idx = it * 256 + t;               // 16B-slot index, 32 slots/row
        int r = idx >> 5, c = idx & 31;
        short8 v = *(const short8*)(gsrc + (size_t)r * 256 + c * 8);
        *(short8*)&q0t[r * 264 + c * 8] = v;
    }
    vcur[t] = 1.0f;
    float vpriv = 1.0f;
    __syncthreads();

    int r = t >> 2, q = t & 3;
    float uown = 0.f;
    const float uinit = 1.0f / (Tg[grp] + EPS);

    for (int p = 1; p <= 5; p++) {
        // ---- row sums with current v (4 lanes per row), stash q0 in regs ----
        short8 st[8];
        float sr = 0.f;
        #pragma unroll
        for (int i = 0; i < 8; i++) {
            st[i] = *(const short8*)&q0t[r * 264 + q * 64 + i * 8];
            const float* vv = &vcur[q * 64 + i * 8];
            sr += bf2f((unsigned short)st[i][0]) * vv[0] + bf2f((unsigned short)st[i][1]) * vv[1]
                + bf2f((unsigned short)st[i][2]) * vv[2] + bf2f((unsigned short)st[i][3]) * vv[3]
                + bf2f((unsigned short)st[i][4]) * vv[4] + bf2f((unsigned short)st[i][5]) * vv[5]
                + bf2f((unsigned short)st[i][6]) * vv[6] + bf2f((unsigned short)st[i][7]) * vv[7];
        }
        sr += __shfl_xor(sr, 1);
        sr += __shfl_xor(sr, 2);
        float up = (p == 1) ? uinit : uown;
        uown = up * (1.0f / 1024.0f) / (up * sr + EPS);

        // ---- column-sum partials: shuffle-reduce the 16 row-lanes of each q-group ----
        #pragma unroll
        for (int i = 0; i < 64; i++) {
            float prod = bf2f((unsigned short)st[i >> 3][i & 7]) * uown;
            prod += __shfl_xor(prod, 4);
            prod += __shfl_xor(prod, 8);
            prod += __shfl_xor(prod, 16);
            prod += __shfl_xor(prod, 32);
            if (lane < 4) wacc[wv][lane * 64 + i] = prod;   // lane==q here (r_local==0)
        }
        __syncthreads();
        float ssum = wacc[0][t] + wacc[1][t] + wacc[2][t] + wacc[3][t];
        atomicAdd(&Sc[((size_t)(p - 1) * 32 + grp) * 256 + t], ssum);
        __syncthreads();                       // drain all atomics (vmcnt(0) before barrier)

        // ---- group barrier across the 16 blocks of (b,mod) ----
        if (t == 0) {
            __threadfence();
            atomicAdd(&ctr[(p - 1) * 32 + grp], 1);
            while (__hip_atomic_load(&ctr[(p - 1) * 32 + grp],
                                     __ATOMIC_ACQUIRE, __HIP_MEMORY_SCOPE_AGENT) < 16)
                __builtin_amdgcn_s_sleep(4);
            __threadfence();
        }
        __syncthreads();

        // ---- v update from completed Sc[p] ----
        float sc = __hip_atomic_load(&Sc[((size_t)(p - 1) * 32 + grp) * 256 + t],
                                     __ATOMIC_RELAXED, __HIP_MEMORY_SCOPE_AGENT);
        vpriv = vpriv * (1.0f / 256.0f) / (vpriv * sc + EPS);
        vcur[t] = vpriv;
        __syncthreads();
    }

    // ---- final row-normalize: u_f ----
    {
        float sr = 0.f;
        #pragma unroll
        for (int i = 0; i < 8; i++) {
            short8 sv = *(const short8*)&q0t[r * 264 + q * 64 + i * 8];
            const float* vv = &vcur[q * 64 + i * 8];
            sr += bf2f((unsigned short)sv[0]) * vv[0] + bf2f((unsigned short)sv[1]) * vv[1]
                + bf2f((unsigned short)sv[2]) * vv[2] + bf2f((unsigned short)sv[3]) * vv[3]
                + bf2f((unsigned short)sv[4]) * vv[4] + bf2f((unsigned short)sv[5]) * vv[5]
                + bf2f((unsigned short)sv[6]) * vv[6] + bf2f((unsigned short)sv[7]) * vv[7];
        }
        sr += __shfl_xor(sr, 1);
        sr += __shfl_xor(sr, 2);
        float uf = uown / (uown * sr + EPS);
        if (q == 0) unl[r] = uf;
    }
    __syncthreads();

    // ---- write assign (f32 + bf16) with coalesced rows; accumulate colsums ----
    float* aout = doutf + OUT_ASSIGN + (size_t)mod * PM;
    unsigned short* ab = abf + (size_t)mod * PM;
    float4 vv4 = *(const float4*)&vcur[lane * 4];
    float c0 = 0.f, c1 = 0.f, c2 = 0.f, c3 = 0.f;
    #pragma unroll
    for (int rr = 0; rr < 16; rr++) {
        int row = wv * 16 + rr;
        float ur = unl[row];
        ushort4 qv = *(const ushort4*)&q0t[row * 264 + lane * 4];
        float4 a = make_float4(bf2f(qv.x) * ur * vv4.x, bf2f(qv.y) * ur * vv4.y,
                               bf2f(qv.z) * ur * vv4.z, bf2f(qv.w) * ur * vv4.w);
        size_t ro = (rowbase + row) * 256;
        *(float4*)(aout + ro + lane * 4) = a;
        ushort4 o;
        o.x = f2bf(a.x); o.y = f2bf(a.y); o.z = f2bf(a.z); o.w = f2bf(a.w);
        *(ushort4*)(ab + ro + lane * 4) = o;
        c0 += a.x; c1 += a.y; c2 += a.z; c3 += a.w;
    }
    *(float4*)&wacc[wv][lane * 4] = make_float4(c0, c1, c2, c3);
    __syncthreads();
    {
        float ssum = wacc[0][t] + wacc[1][t] + wacc[2][t] + wacc[3][t];
        atomicAdd(&cs[(size_t)grp * 256 + t], ssum);
    }
}

// ---------------- sem consistency scalar ----------------
__global__ __launch_bounds__(256) void sem_kernel(const float* __restrict__ cs,
                                                  float* __restrict__ doutf) {
    int t = threadIdx.x;
    float s = 0.f;
    #pragma unroll
    for (int b = 0; b < 16; b++)
        s += cs[b * 256 + t] * cs[4096 + b * 256 + t];
    #pragma unroll
    for (int mk = 1; mk < 64; mk <<= 1) s += __shfl_xor(s, mk);
    __shared__ float red[4];
    if ((t & 63) == 0) red[t >> 6] = s;
    __syncthreads();
    if (t == 0) {
        float tot = red[0] + red[1] + red[2] + red[3];
        float mv = tot / 16777216.0f;           // B*N*N
        mv = fminf(fmaxf(mv, 0.f), 1.f);
        doutf[OUT_SEM] = 1.0f - mv;
    }
}

extern "C" void kernel_launch(void* const* d_in, const int* in_sizes, int n_in,
                              void* d_out, int out_size, void* d_ws, size_t ws_size,
                              hipStream_t stream) {
    const float* f_rgb = (const float*)d_in[0];
    const float* f_sn  = (const float*)d_in[1];
    const float* p_rgb = (const float*)d_in[2];
    const float* p_sn  = (const float*)d_in[3];
    char* ws = (char*)d_ws;
    unsigned short* xn   = (unsigned short*)(ws + OFF_XN);
    unsigned short* abf  = (unsigned short*)(ws + OFF_XN);   // aliases xn (dead after gemm0)
    unsigned short* qb   = (unsigned short*)(ws + OFF_QB);
    unsigned short* pn   = (unsigned short*)(ws + OFF_PN);
    unsigned short* pnt  = (unsigned short*)(ws + OFF_PNT);
    float* Tg            = (float*)(ws + OFF_T);
    float* Sc            = (float*)(ws + OFF_SC);
    float* cs            = (float*)(ws + OFF_CS);
    int*   ctr           = (int*)(ws + OFF_CTR);
    float* doutf         = (float*)d_out;

    proto_kernel<<<dim3(512), 64, 0, stream>>>(p_rgb, p_sn, pn, pnt, (float*)(ws + ZERO_OFF));
    prep_kernel<<<dim3(4096, 2), 256, 0, stream>>>(f_rgb, f_sn, xn);
    gemm_kernel<0><<<dim3(2, 128, 2), 256, 0, stream>>>(xn, pn, qb, doutf, Tg);
    sinkhorn_kernel<<<dim3(16, 16, 2), 256, 0, stream>>>(qb, Tg, Sc, ctr, cs, doutf, abf);
    gemm_kernel<1><<<dim3(2, 128, 2), 256, 0, stream>>>(abf, pnt, qb, doutf, Tg);
    sem_kernel<<<1, 256, 0, stream>>>(cs, doutf);
}